// Round 1
// baseline (336.308 us; speedup 1.0000x reference)
//
#include <hip/hip_runtime.h>

#define K_DIM 2048
#define N_DIM 2048
#define M_DIM 16384

typedef int v4i __attribute__((ext_vector_type(4)));

// ---------------- ws layout ----------------
// [0]       double wsum
// [8]       float invsw (= clip(mean|W|,1e-5) ~= 1/sw)
// [256]     float si[16384]            (65536 B)
// [65792]   int8  qw[2048*2048]        (4 MiB)
// [4260096] int8  qx[16384*2048]       (32 MiB)
// total ~37.8 MB

__device__ __forceinline__ void lds16(const void* g, void* l) {
    __builtin_amdgcn_global_load_lds(
        (const __attribute__((address_space(1))) unsigned int*)g,
        (__attribute__((address_space(3))) unsigned int*)l,
        16, 0, 0);
}

// ---------- kernel 1: sum |W| in double ----------
__global__ __launch_bounds__(256) void k_wsum(const float* __restrict__ w,
                                              double* __restrict__ wsum) {
    int tid = blockIdx.x * 256 + threadIdx.x;
    int stride = gridDim.x * 256;
    const float4* w4 = (const float4*)w;
    double s = 0.0;
    for (int i = tid; i < (N_DIM * K_DIM / 4); i += stride) {
        float4 v = w4[i];
        s += (double)fabsf(v.x);
        s += (double)fabsf(v.y);
        s += (double)fabsf(v.z);
        s += (double)fabsf(v.w);
    }
#pragma unroll
    for (int off = 32; off; off >>= 1) s += __shfl_xor(s, off, 64);
    __shared__ double part[4];
    int lane = threadIdx.x & 63, wv = threadIdx.x >> 6;
    if (lane == 0) part[wv] = s;
    __syncthreads();
    if (threadIdx.x == 0) atomicAdd(wsum, part[0] + part[1] + part[2] + part[3]);
}

// ---------- kernel 2: ternary-quantize W ----------
__global__ __launch_bounds__(256) void k_quant_w(const float* __restrict__ w,
                                                 signed char* __restrict__ qw,
                                                 const double* __restrict__ wsum,
                                                 float* __restrict__ invsw_out) {
    float mean = (float)(*wsum * (1.0 / (double)(N_DIM * K_DIM)));
    float meanc = fmaxf(mean, 1e-5f);
    float sw = 1.0f / meanc;  // reference's sw
    int tid = blockIdx.x * 256 + threadIdx.x;
    float4 v = ((const float4*)w)[tid];
    int q0 = (int)fminf(fmaxf(rintf(v.x * sw), -1.f), 1.f);
    int q1 = (int)fminf(fmaxf(rintf(v.y * sw), -1.f), 1.f);
    int q2 = (int)fminf(fmaxf(rintf(v.z * sw), -1.f), 1.f);
    int q3 = (int)fminf(fmaxf(rintf(v.w * sw), -1.f), 1.f);
    ((int*)qw)[tid] = (q0 & 255) | ((q1 & 255) << 8) | ((q2 & 255) << 16) | ((q3 & 255) << 24);
    if (tid == 0) *invsw_out = meanc;  // multiply by this ~= divide by sw
}

// ---------- kernel 3: per-row int8-quantize X (1 wave per row) ----------
__global__ __launch_bounds__(256) void k_quant_x(const float* __restrict__ x,
                                                 signed char* __restrict__ qx,
                                                 float* __restrict__ si_out) {
    int row = blockIdx.x * 4 + (threadIdx.x >> 6);
    int lane = threadIdx.x & 63;
    const float4* xr = (const float4*)(x + (size_t)row * K_DIM);
    float4 v[8];
    float mx = 0.f;
#pragma unroll
    for (int c = 0; c < 8; c++) {
        v[c] = xr[c * 64 + lane];
        mx = fmaxf(mx, fmaxf(fmaxf(fabsf(v[c].x), fabsf(v[c].y)),
                             fmaxf(fabsf(v[c].z), fabsf(v[c].w))));
    }
#pragma unroll
    for (int off = 32; off; off >>= 1) mx = fmaxf(mx, __shfl_xor(mx, off, 64));
    float si = 127.0f / fmaxf(mx, 1e-5f);  // bit-exact vs reference
    if (lane == 0) si_out[row] = si;
    int* qr = (int*)(qx + (size_t)row * K_DIM);
#pragma unroll
    for (int c = 0; c < 8; c++) {
        int q0 = (int)fminf(fmaxf(rintf(v[c].x * si), -128.f), 127.f);
        int q1 = (int)fminf(fmaxf(rintf(v[c].y * si), -128.f), 127.f);
        int q2 = (int)fminf(fmaxf(rintf(v[c].z * si), -128.f), 127.f);
        int q3 = (int)fminf(fmaxf(rintf(v[c].w * si), -128.f), 127.f);
        qr[c * 64 + lane] = (q0 & 255) | ((q1 & 255) << 8) | ((q2 & 255) << 16) | ((q3 & 255) << 24);
    }
}

// ---------- kernel 4: int8 GEMM (m97 structure), fused dequant epilogue ----------
// C[m][n] = sum_k qx[m][k] * qw[n][k]; out = fp16_round(C * (1/si) * invsw)
__global__ __launch_bounds__(256) void k_gemm(const signed char* __restrict__ qx,
                                              const signed char* __restrict__ qw,
                                              const float* __restrict__ si,
                                              const float* __restrict__ invsw_p,
                                              float* __restrict__ out) {
    __shared__ __align__(16) signed char As[128 * 64];  // [row][k] 8KB
    __shared__ __align__(16) signed char Bs[128 * 64];  // [n][k]   8KB
    const int t = threadIdx.x;
    const int lane = t & 63, wv = t >> 6;
    const int wr = wv >> 1, wc = wv & 1;       // wave 2x2 grid, each 64x64
    const int lr = lane & 15, lq = lane >> 4;  // MFMA row / k-quad
    const int bm = blockIdx.y, bn = blockIdx.x;

    // staging map: thread t loads 16B -> LDS offset t*16 (wave-uniform base + lane*16)
    const int sRow = t >> 2;
    const int sCol = (t & 3) << 4;
    const signed char* aB0 = qx + (size_t)(bm * 128 + sRow) * K_DIM + sCol;
    const signed char* aB1 = aB0 + (size_t)64 * K_DIM;
    const signed char* bB0 = qw + (size_t)(bn * 128 + sRow) * K_DIM + sCol;
    const signed char* bB1 = bB0 + (size_t)64 * K_DIM;
    const int t16 = t << 4;

    v4i acc[4][4] = {};

    for (int k0 = 0; k0 < K_DIM; k0 += 64) {
        lds16(aB0 + k0, (signed char*)As + t16);
        lds16(aB1 + k0, (signed char*)As + 4096 + t16);
        lds16(bB0 + k0, (signed char*)Bs + t16);
        lds16(bB1 + k0, (signed char*)Bs + 4096 + t16);
        __syncthreads();  // staging done, LDS visible

        v4i af[4], bf[4];
#pragma unroll
        for (int mt = 0; mt < 4; mt++)
            af[mt] = *(const v4i*)(As + ((wr * 64 + mt * 16 + lr) * 64 + lq * 16));
#pragma unroll
        for (int nt = 0; nt < 4; nt++)
            bf[nt] = *(const v4i*)(Bs + ((wc * 64 + nt * 16 + lr) * 64 + lq * 16));
#pragma unroll
        for (int mt = 0; mt < 4; mt++)
#pragma unroll
            for (int nt = 0; nt < 4; nt++)
                acc[mt][nt] = __builtin_amdgcn_mfma_i32_16x16x64_i8(af[mt], bf[nt], acc[mt][nt], 0, 0, 0);
        __syncthreads();  // all waves done reading before next stage
    }

    // epilogue: dequant + fp16 round, store fp32
    float invsw = *invsw_p;
#pragma unroll
    for (int mt = 0; mt < 4; mt++) {
        int rowb = bm * 128 + wr * 64 + mt * 16 + lq * 4;
        float sc[4];
#pragma unroll
        for (int r = 0; r < 4; r++) sc[r] = invsw / si[rowb + r];
#pragma unroll
        for (int nt = 0; nt < 4; nt++) {
            int col = bn * 128 + wc * 64 + nt * 16 + lr;
#pragma unroll
            for (int r = 0; r < 4; r++) {
                float vv = (float)acc[mt][nt][r] * sc[r];
                out[(size_t)(rowb + r) * N_DIM + col] = (float)(_Float16)vv;
            }
        }
    }
}

extern "C" void kernel_launch(void* const* d_in, const int* in_sizes, int n_in,
                              void* d_out, int out_size, void* d_ws, size_t ws_size,
                              hipStream_t stream) {
    const float* x = (const float*)d_in[0];
    const float* w = (const float*)d_in[1];
    float* out = (float*)d_out;
    char* ws = (char*)d_ws;

    double* wsum = (double*)ws;
    float* invsw = (float*)(ws + 8);
    float* si = (float*)(ws + 256);
    signed char* qw = (signed char*)(ws + 256 + 65536);
    signed char* qx = qw + (size_t)N_DIM * K_DIM;

    hipMemsetAsync(wsum, 0, 8, stream);
    k_wsum<<<1024, 256, 0, stream>>>(w, wsum);
    k_quant_w<<<4096, 256, 0, stream>>>(w, qw, wsum, invsw);
    k_quant_x<<<4096, 256, 0, stream>>>(x, qx, si);
    k_gemm<<<dim3(N_DIM / 128, M_DIM / 128), 256, 0, stream>>>(qx, qw, si, invsw, out);
}